// Round 6
// baseline (2138.946 us; speedup 1.0000x reference)
//
#include <hip/hip_runtime.h>
#include <hip/hip_bf16.h>

// Problem constants
#define BB 16
#define LL 1024
#define DD 384
#define FF 1536
#define KK 3
#define T_OUT 10240
#define MAX_DUR 10

#define PADL 1026                 // per-batch padded rows: [0]=zero, [1..1024]=data, [1025]=zero
#define LO_SCALE 2048.0f          // 2^11: keeps lo parts out of fp16-denormal range
#define LO_INV   4.8828125e-4f    // 2^-11

typedef _Float16 f16x8 __attribute__((ext_vector_type(8)));
typedef float    f32x4 __attribute__((ext_vector_type(4)));

__device__ __forceinline__ void split_write(float v, _Float16* hi, _Float16* lo, size_t off) {
    _Float16 h = (_Float16)v;
    hi[off] = h;
    lo[off] = (_Float16)((v - (float)h) * LO_SCALE);
}

__device__ __forceinline__ float split_read(const _Float16* hi, const _Float16* lo, size_t off) {
    return (float)hi[off] + (float)lo[off] * LO_INV;
}

// ---- weight pack: (O,I,3) -> MFMA-fragment-major hi/lo --------------------
// frag layout: [o_tile16][ktl][lane][e8], 8 halfs/lane (16 B): a wave's b-frag
// load is base + lane*16 (one coalesced global_load_dwordx4).
// ktl ordering matches the GEMM k-loop: kseg = ktl%3 (fastest), d0 = (ktl/3)*32.
__global__ void wfrag_k(const float* __restrict__ w, _Float16* __restrict__ hi,
                        _Float16* __restrict__ lo, int O, int I) {
    int id = blockIdx.x * 256 + threadIdx.x;
    int total = O * 3 * I;
    if (id >= total) return;
    int e = id & 7;
    int lane = (id >> 3) & 63;
    int rest = id >> 9;              // o_tile * nKT + ktl
    int nKT = (3 * I) >> 5;
    int ktl = rest % nKT;
    int ot = rest / nKT;
    int o = ot * 16 + (lane & 15);
    int koff = ((lane >> 4) << 3) + e;
    int kseg = ktl % 3;
    int i = (ktl / 3) * 32 + koff;
    float v = w[(o * I + i) * 3 + kseg];
    split_write(v, hi, lo, id);
}

// ---------------- y split into padded hi/lo layout ---------------------------
__global__ void ysplit_k(const float* __restrict__ y, _Float16* __restrict__ hi,
                         _Float16* __restrict__ lo) {
    int id = blockIdx.x * 256 + threadIdx.x;     // BB*PADL*DD
    if (id >= BB * PADL * DD) return;
    int d = id % DD;
    int r = id / DD;
    int b = r / PADL;
    int lr = r - b * PADL;
    float v = 0.f;
    if (lr >= 1 && lr <= LL) v = y[((size_t)(b << 10) + (lr - 1)) * DD + d];
    split_write(v, hi, lo, id);
}

// ---------------- zero the halo pad rows of a padded split buffer ------------
__global__ void padzero_k(_Float16* __restrict__ hi, _Float16* __restrict__ lo, int width) {
    int id = blockIdx.x * 256 + threadIdx.x;     // BB*2*width
    if (id >= BB * 2 * width) return;
    int b = id / (2 * width);
    int rem = id - b * 2 * width;
    int row = (rem / width) ? (PADL - 1) : 0;
    int c = rem % width;
    size_t off = (size_t)(b * PADL + row) * width + c;
    hi[off] = (_Float16)0.f;
    lo[off] = (_Float16)0.f;
}

// ---------------- split-fp16 MFMA conv-GEMM: barrier-free, LDS-free ----------
// Block 128x64, 4 waves of 64x32. All fragments loaded global->register:
//  A from padded [row][d] buffer: lane (m=lane&15, kq=lane>>4) reads 16 B at
//    (rowBase+m+kseg)*Cin + d0 + kq*8 -> 16 x 64 B lines/instr (fully packed).
//  B from fragment-major pack (contiguous 16 B/lane).
// K-loop software-pipelined x2 with register double-buffer; no __syncthreads
// anywhere -> no vmcnt(0) drain; compiler overlaps loads of kt+1 with MFMAs
// of kt using per-use waitcnt.
__global__ __launch_bounds__(256, 2) void gemm_split(
        const _Float16* __restrict__ Ahi, const _Float16* __restrict__ Alo,
        const _Float16* __restrict__ WfH, const _Float16* __restrict__ WfL,
        const float* __restrict__ bias,
        _Float16* __restrict__ Ohi, _Float16* __restrict__ Olo,
        int Cin, int Cout, int Ktot, int nN) {
    const int tid = threadIdx.x;
    const int lane = tid & 63;
    const int w = tid >> 6;
    const int lm = lane & 15, lq = lane >> 4;
    // XCD-aware remap: group-of-4 m-tiles, n fastest inside the group
    const int xcd = blockIdx.x & 7;
    const int t2 = blockIdx.x >> 3;
    const int g  = t2 / (4 * nN);
    const int r  = t2 - g * (4 * nN);
    const int n_t = r >> 2;
    const int mi  = r & 3;
    const int m_t = ((g * 4 + mi) << 3) + xcd;
    const int m0 = m_t << 7;
    const int n0 = n_t << 6;
    const int b = m0 >> 10;
    const int l0 = m0 & 1023;
    const int rowBase = b * PADL + l0;           // + m + kseg = padded source row
    const int wm = (w >> 1) * 64, wn = (w & 1) * 32;

    f32x4 accM[4][2], accC[4][2];
    const f32x4 zz = {0.f, 0.f, 0.f, 0.f};
    #pragma unroll
    for (int i = 0; i < 4; ++i)
        #pragma unroll
        for (int jj = 0; jj < 2; ++jj) { accM[i][jj] = zz; accC[i][jj] = zz; }

    const int nKT = Ktot >> 5;
    // lane-fixed base: row = rowBase + wm + lm (+ i*16 + kseg), col = lq*8 (+ d0)
    const size_t aLaneOff = (size_t)(rowBase + wm + lm) * Cin + lq * 8;

    auto loadAB = [&](int kt, f16x8* aH, f16x8* aL, f16x8* bH, f16x8* bL) {
        int ktc = kt < nKT ? kt : nKT - 1;
        int kd = ktc / 3;
        int kseg = ktc - kd * 3;
        int d0 = kd << 5;
        const _Float16* ah = Ahi + aLaneOff + (size_t)kseg * Cin + d0;
        const _Float16* al = Alo + aLaneOff + (size_t)kseg * Cin + d0;
        #pragma unroll
        for (int i = 0; i < 4; ++i) {
            aH[i] = *(const f16x8*)(ah + (size_t)(i * 16) * Cin);
            aL[i] = *(const f16x8*)(al + (size_t)(i * 16) * Cin);
        }
        #pragma unroll
        for (int jj = 0; jj < 2; ++jj) {
            int ntg = (n0 + wn + jj * 16) >> 4;
            size_t boff = (((size_t)ntg * nKT + ktc) * 64 + lane) * 8;
            bH[jj] = *(const f16x8*)(WfH + boff);
            bL[jj] = *(const f16x8*)(WfL + boff);
        }
    };

    auto compute = [&](const f16x8* aH, const f16x8* aL,
                       const f16x8* bH, const f16x8* bL) {
        #pragma unroll
        for (int i = 0; i < 4; ++i)
            #pragma unroll
            for (int jj = 0; jj < 2; ++jj) {
                accM[i][jj] = __builtin_amdgcn_mfma_f32_16x16x32_f16(aH[i], bH[jj], accM[i][jj], 0, 0, 0);
                accC[i][jj] = __builtin_amdgcn_mfma_f32_16x16x32_f16(aH[i], bL[jj], accC[i][jj], 0, 0, 0);
                accC[i][jj] = __builtin_amdgcn_mfma_f32_16x16x32_f16(aL[i], bH[jj], accC[i][jj], 0, 0, 0);
            }
    };

    f16x8 a0H[4], a0L[4], b0H[2], b0L[2];
    f16x8 a1H[4], a1L[4], b1H[2], b1L[2];
    loadAB(0, a0H, a0L, b0H, b0L);
    for (int kt = 0; kt < nKT; kt += 2) {        // nKT is even (36 or 144)
        loadAB(kt + 1, a1H, a1L, b1H, b1L);
        compute(a0H, a0L, b0H, b0L);
        loadAB(kt + 2, a0H, a0L, b0H, b0L);
        compute(a1H, a1L, b1H, b1L);
    }
    // epilogue: bias + relu + re-split to padded hi/lo output
    #pragma unroll
    for (int i = 0; i < 4; ++i)
        #pragma unroll
        for (int jj = 0; jj < 2; ++jj) {
            int n_g = n0 + wn + jj * 16 + lm;
            float bv = bias[n_g];
            #pragma unroll
            for (int rr = 0; rr < 4; ++rr) {
                int l = l0 + wm + i * 16 + lq * 4 + rr;
                float v = accM[i][jj][rr] + accC[i][jj][rr] * LO_INV + bv;
                v = fmaxf(v, 0.f);
                size_t off = (size_t)(b * PADL + 1 + l) * Cout + n_g;
                split_write(v, Ohi, Olo, off);
            }
        }
}

// ---------------- layernorm in place on split buffer (width 384) -------------
__global__ __launch_bounds__(128) void ln_split_k(
        _Float16* __restrict__ hi, _Float16* __restrict__ lo,
        const float* __restrict__ g, const float* __restrict__ be) {
    const int row = blockIdx.x;
    const int b = row >> 10, l = row & 1023;
    const size_t base = (size_t)(b * PADL + 1 + l) * DD;
    const int tid = threadIdx.x;
    float v0 = split_read(hi, lo, base + tid);
    float v1 = split_read(hi, lo, base + tid + 128);
    float v2 = split_read(hi, lo, base + tid + 256);

    __shared__ float sh[2];
    float s = v0 + v1 + v2;
    #pragma unroll
    for (int o = 32; o > 0; o >>= 1) s += __shfl_down(s, o, 64);
    if ((tid & 63) == 0) sh[tid >> 6] = s;
    __syncthreads();
    float mu = (sh[0] + sh[1]) * (1.f / DD);
    __syncthreads();
    float d0 = v0 - mu, d1 = v1 - mu, d2 = v2 - mu;
    float q = d0 * d0 + d1 * d1 + d2 * d2;
    #pragma unroll
    for (int o = 32; o > 0; o >>= 1) q += __shfl_down(q, o, 64);
    if ((tid & 63) == 0) sh[tid >> 6] = q;
    __syncthreads();
    float var = (sh[0] + sh[1]) * (1.f / DD);
    float rs = rsqrtf(var + 1e-5f);
    split_write(d0 * rs * g[tid] + be[tid], hi, lo, base + tid);
    split_write(d1 * rs * g[tid + 128] + be[tid + 128], hi, lo, base + tid + 128);
    split_write(d2 * rs * g[tid + 256] + be[tid + 256], hi, lo, base + tid + 256);
}

// ---------------- layernorm + length predictor on split buffer ---------------
__global__ __launch_bounds__(128) void ln_pred_split_k(
        const _Float16* __restrict__ hi, const _Float16* __restrict__ lo,
        const float* __restrict__ g, const float* __restrict__ be,
        const float* __restrict__ wl, const float* __restrict__ bl,
        const int* __restrict__ token_lengths, int* __restrict__ lns) {
    const int row = blockIdx.x;
    const int b = row >> 10, l = row & 1023;
    const size_t base = (size_t)(b * PADL + 1 + l) * DD;
    const int tid = threadIdx.x;
    float v0 = split_read(hi, lo, base + tid);
    float v1 = split_read(hi, lo, base + tid + 128);
    float v2 = split_read(hi, lo, base + tid + 256);

    __shared__ float sh[2];
    float s = v0 + v1 + v2;
    #pragma unroll
    for (int o = 32; o > 0; o >>= 1) s += __shfl_down(s, o, 64);
    if ((tid & 63) == 0) sh[tid >> 6] = s;
    __syncthreads();
    float mu = (sh[0] + sh[1]) * (1.f / DD);
    __syncthreads();
    float d0 = v0 - mu, d1 = v1 - mu, d2 = v2 - mu;
    float q = d0 * d0 + d1 * d1 + d2 * d2;
    #pragma unroll
    for (int o = 32; o > 0; o >>= 1) q += __shfl_down(q, o, 64);
    if ((tid & 63) == 0) sh[tid >> 6] = q;
    __syncthreads();
    float var = (sh[0] + sh[1]) * (1.f / DD);
    float rs = rsqrtf(var + 1e-5f);
    __syncthreads();
    float p = (d0 * rs * g[tid]       + be[tid])       * wl[tid]
            + (d1 * rs * g[tid + 128] + be[tid + 128]) * wl[tid + 128]
            + (d2 * rs * g[tid + 256] + be[tid + 256]) * wl[tid + 256];
    #pragma unroll
    for (int o = 32; o > 0; o >>= 1) p += __shfl_down(p, o, 64);
    if ((tid & 63) == 0) sh[tid >> 6] = p;
    __syncthreads();
    if (tid == 0) {
        float pred = sh[0] + sh[1] + bl[0];
        float e = expf(pred);           // ALPHA == 1.0
        float r = rintf(e);             // round-half-even, matches jnp.round
        r = fminf(fmaxf(r, 0.f), (float)MAX_DUR);
        int v = (int)r;
        if (l >= token_lengths[b]) v = 0;
        lns[row] = v;
    }
}

// ---------------- per-batch inclusive cumsum (L=1024) ------------------------
__global__ __launch_bounds__(1024) void cumsum_k(
        const int* __restrict__ lns, int* __restrict__ csum,
        float* __restrict__ totals_out) {
    __shared__ int s[1024];
    const int b = blockIdx.x, tid = threadIdx.x;
    s[tid] = lns[(b << 10) + tid];
    __syncthreads();
    #pragma unroll
    for (int o = 1; o < 1024; o <<= 1) {
        int t = (tid >= o) ? s[tid - o] : 0;
        __syncthreads();
        s[tid] += t;
        __syncthreads();
    }
    csum[(b << 10) + tid] = s[tid];
    if (tid == 1023) totals_out[b] = (float)s[1023];
}

// ---------------- gather: out[b,t,:] = valid ? y[b, idx(t), :] : 0 -----------
__global__ __launch_bounds__(256) void gather_k(
        const float* __restrict__ y, const int* __restrict__ csum,
        float* __restrict__ out) {
    int gid = blockIdx.x * 256 + threadIdx.x;   // B*T_OUT*96 float4 chunks
    int c4 = gid % 96;
    int rest = gid / 96;
    int t = rest % T_OUT;
    int b = rest / T_OUT;
    const int* c = csum + (b << 10);
    int total = c[1023];
    float4 r = make_float4(0.f, 0.f, 0.f, 0.f);
    if (t < total) {
        int lo = 0, hi = 1024;
        while (lo < hi) {               // searchsorted side='right'
            int mid = (lo + hi) >> 1;
            if (c[mid] <= t) lo = mid + 1; else hi = mid;
        }
        int idx = min(lo, LL - 1);
        r = *(const float4*)(y + ((size_t)((b << 10) + idx)) * DD + (c4 << 2));
    }
    *(float4*)(out + ((size_t)b * T_OUT + t) * DD + (c4 << 2)) = r;
}

// ---------------- host side --------------------------------------------------
extern "C" void kernel_launch(void* const* d_in, const int* in_sizes, int n_in,
                              void* d_out, int out_size, void* d_ws, size_t ws_size,
                              hipStream_t stream) {
    const float* y   = (const float*)d_in[0];
    const int*   tok = (const int*)d_in[1];
    const float* w1a = (const float*)d_in[2];
    const float* b1a = (const float*)d_in[3];
    const float* w1b = (const float*)d_in[4];
    const float* b1b = (const float*)d_in[5];
    const float* g1  = (const float*)d_in[6];
    const float* be1 = (const float*)d_in[7];
    const float* w2a = (const float*)d_in[8];
    const float* b2a = (const float*)d_in[9];
    const float* w2b = (const float*)d_in[10];
    const float* b2b = (const float*)d_in[11];
    const float* g2  = (const float*)d_in[12];
    const float* be2 = (const float*)d_in[13];
    const float* wl  = (const float*)d_in[14];
    const float* bl  = (const float*)d_in[15];

    float* out = (float*)d_out;

    // workspace layout (halfs)
    const size_t WN   = (size_t)FF * DD * KK;          // 1,769,472 per weight comp
    const size_t SN   = (size_t)BB * PADL * DD;        // 6,303,744
    const size_t H1N  = (size_t)BB * PADL * FF;        // 25,214,976
    _Float16* p = (_Float16*)d_ws;
    _Float16* Wh1a = p;              _Float16* Wl1a = Wh1a + WN;
    _Float16* Wh1b = Wl1a + WN;      _Float16* Wl1b = Wh1b + WN;
    _Float16* Wh2a = Wl1b + WN;      _Float16* Wl2a = Wh2a + WN;
    _Float16* Wh2b = Wl2a + WN;      _Float16* Wl2b = Wh2b + WN;
    _Float16* Shi  = Wl2b + WN;      _Float16* Slo  = Shi + SN;
    _Float16* H1hi = Slo + SN;       _Float16* H1lo = H1hi + H1N;
    int* lns  = (int*)(H1lo + H1N);
    int* csum = lns + BB * LL;

    const int M = BB * LL;                              // 16384

    // 1) weight frag-pack+split, y split, pad-zero for H1
    {
        int n = FF * DD * KK;
        wfrag_k<<<(n + 255) / 256, 256, 0, stream>>>(w1a, Wh1a, Wl1a, FF, DD);
        wfrag_k<<<(n + 255) / 256, 256, 0, stream>>>(w1b, Wh1b, Wl1b, DD, FF);
        wfrag_k<<<(n + 255) / 256, 256, 0, stream>>>(w2a, Wh2a, Wl2a, FF, DD);
        wfrag_k<<<(n + 255) / 256, 256, 0, stream>>>(w2b, Wh2b, Wl2b, DD, FF);
        int ny = BB * PADL * DD;
        ysplit_k<<<(ny + 255) / 256, 256, 0, stream>>>(y, Shi, Slo);
        int np = BB * 2 * FF;
        padzero_k<<<(np + 255) / 256, 256, 0, stream>>>(H1hi, H1lo, FF);
    }
    // 2) four conv-GEMMs (1-D grids, XCD-remapped in-kernel; block 128x64)
    gemm_split<<<(M / 128) * (FF / 64), 256, 0, stream>>>(Shi, Slo, Wh1a, Wl1a, b1a, H1hi, H1lo, DD, FF, 3 * DD, FF / 64);
    gemm_split<<<(M / 128) * (DD / 64), 256, 0, stream>>>(H1hi, H1lo, Wh1b, Wl1b, b1b, Shi, Slo, FF, DD, 3 * FF, DD / 64);
    ln_split_k<<<M, 128, 0, stream>>>(Shi, Slo, g1, be1);
    gemm_split<<<(M / 128) * (FF / 64), 256, 0, stream>>>(Shi, Slo, Wh2a, Wl2a, b2a, H1hi, H1lo, DD, FF, 3 * DD, FF / 64);
    gemm_split<<<(M / 128) * (DD / 64), 256, 0, stream>>>(H1hi, H1lo, Wh2b, Wl2b, b2b, Shi, Slo, FF, DD, 3 * FF, DD / 64);
    // 3) predictor + cumsum + gather
    ln_pred_split_k<<<M, 128, 0, stream>>>(Shi, Slo, g2, be2, wl, bl, tok, lns);
    cumsum_k<<<BB, 1024, 0, stream>>>(lns, csum, out + (size_t)BB * T_OUT * DD);
    {
        long long n = (long long)BB * T_OUT * 96;
        gather_k<<<(int)((n + 255) / 256), 256, 0, stream>>>(y, csum, out);
    }
}

// Round 7
// 1143.198 us; speedup vs baseline: 1.8710x; 1.8710x over previous
//
#include <hip/hip_runtime.h>
#include <hip/hip_bf16.h>

// Problem constants
#define BB 16
#define LL 1024
#define DD 384
#define FF 1536
#define KK 3
#define T_OUT 10240
#define MAX_DUR 10

#define PADL 1026                 // per-batch padded rows: [0]=zero, [1..1024]=data, [1025]=zero
#define LO_SCALE 2048.0f          // 2^11: keeps lo parts out of fp16-denormal range
#define LO_INV   4.8828125e-4f    // 2^-11

typedef _Float16 f16x8 __attribute__((ext_vector_type(8)));
typedef float    f32x4 __attribute__((ext_vector_type(4)));

__device__ __forceinline__ void gll16(const void* g, void* l) {
    __builtin_amdgcn_global_load_lds(
        (const __attribute__((address_space(1))) void*)g,
        (__attribute__((address_space(3))) void*)l, 16, 0, 0);
}

__device__ __forceinline__ void split_write(float v, _Float16* hi, _Float16* lo, size_t off) {
    _Float16 h = (_Float16)v;
    hi[off] = h;
    lo[off] = (_Float16)((v - (float)h) * LO_SCALE);
}

__device__ __forceinline__ float split_read(const _Float16* hi, const _Float16* lo, size_t off) {
    return (float)hi[off] + (float)lo[off] * LO_INV;
}

// ---- weight pack: (O,I,3) -> MFMA-fragment-major hi/lo --------------------
// frag layout: [o_tile16][ktl][lane][e8], 8 halfs/lane (16 B): a wave's b-frag
// load is base + lane*16 (one coalesced global_load_dwordx4).
// ktl ordering matches the GEMM k-loop: kseg = ktl%3 (fastest), d0 = (ktl/3)*32.
__global__ void wfrag_k(const float* __restrict__ w, _Float16* __restrict__ hi,
                        _Float16* __restrict__ lo, int O, int I) {
    int id = blockIdx.x * 256 + threadIdx.x;
    int total = O * 3 * I;
    if (id >= total) return;
    int e = id & 7;
    int lane = (id >> 3) & 63;
    int rest = id >> 9;              // o_tile * nKT + ktl
    int nKT = (3 * I) >> 5;
    int ktl = rest % nKT;
    int ot = rest / nKT;
    int o = ot * 16 + (lane & 15);
    int koff = ((lane >> 4) << 3) + e;
    int kseg = ktl % 3;
    int i = (ktl / 3) * 32 + koff;
    float v = w[(o * I + i) * 3 + kseg];
    split_write(v, hi, lo, id);
}

// ---------------- y split into padded hi/lo layout ---------------------------
__global__ void ysplit_k(const float* __restrict__ y, _Float16* __restrict__ hi,
                         _Float16* __restrict__ lo) {
    int id = blockIdx.x * 256 + threadIdx.x;     // BB*PADL*DD
    if (id >= BB * PADL * DD) return;
    int d = id % DD;
    int r = id / DD;
    int b = r / PADL;
    int lr = r - b * PADL;
    float v = 0.f;
    if (lr >= 1 && lr <= LL) v = y[((size_t)(b << 10) + (lr - 1)) * DD + d];
    split_write(v, hi, lo, id);
}

// ---------------- zero the halo pad rows of a padded split buffer ------------
__global__ void padzero_k(_Float16* __restrict__ hi, _Float16* __restrict__ lo, int width) {
    int id = blockIdx.x * 256 + threadIdx.x;     // BB*2*width
    if (id >= BB * 2 * width) return;
    int b = id / (2 * width);
    int rem = id - b * 2 * width;
    int row = (rem / width) ? (PADL - 1) : 0;
    int c = rem % width;
    size_t off = (size_t)(b * PADL + row) * width + c;
    hi[off] = (_Float16)0.f;
    lo[off] = (_Float16)0.f;
}

// ---------------- split-fp16 MFMA conv-GEMM ----------------------------------
// Block tile 128(M) x 64(N), 4 waves of 64x32 -> acc 64 regs/wave, total
// <=128 regs/wave => __launch_bounds__(256,4): 4 waves/SIMD, 4 independent
// blocks/CU. Rationale: the per-k-tile barrier drain (vmcnt(0) before
// s_barrier) is structural; with 4 de-correlated blocks per CU the MFMA pipe
// stays fed while any one block drains.
// A staged via global_load_lds into a 32 KB LDS double buffer (same proven
// swizzle as R3/R4: contiguous for wave-uniform staging, conflict-free b128
// reads). B direct global->reg from fragment-major pack, issued BEFORE the
// barrier so the drain covers its L2 latency.
__global__ __launch_bounds__(256, 4) void gemm_split(
        const _Float16* __restrict__ Ahi, const _Float16* __restrict__ Alo,
        const _Float16* __restrict__ WfH, const _Float16* __restrict__ WfL,
        const float* __restrict__ bias,
        _Float16* __restrict__ Ohi, _Float16* __restrict__ Olo,
        int Cin, int Cout, int Ktot, int nN) {
    __shared__ _Float16 lds_h[16384];   // 32 KB: 2 x (Ahi 8KB | Alo 8KB)
    const int tid = threadIdx.x;
    const int lane = tid & 63;
    const int w = tid >> 6;
    const int lm = lane & 15, lq = lane >> 4;
    // XCD-aware remap: group-of-4 m-tiles, n fastest inside the group
    const int xcd = blockIdx.x & 7;
    const int t2 = blockIdx.x >> 3;
    const int g  = t2 / (4 * nN);
    const int r  = t2 - g * (4 * nN);
    const int n_t = r >> 2;
    const int mi  = r & 3;
    const int m_t = ((g * 4 + mi) << 3) + xcd;
    const int m0 = m_t << 7;
    const int n0 = n_t << 6;
    const int b = m0 >> 10;
    const int l0 = m0 & 1023;
    const int rowBase = b * PADL + l0;           // + m + kseg = padded source row
    const int wm = (w >> 1) * 64, wn = (w & 1) * 32;

    f32x4 accM[4][2], accC[4][2];
    const f32x4 zz = {0.f, 0.f, 0.f, 0.f};
    #pragma unroll
    for (int i = 0; i < 4; ++i)
        #pragma unroll
        for (int jj = 0; jj < 2; ++jj) { accM[i][jj] = zz; accC[i][jj] = zz; }

    const int nKT = Ktot >> 5;

    // stage A k-tile kt into LDS buffer nxt (512 16B-slots per comp)
    auto stageA = [&](int kt, int nxt) {
        int kseg = kt % 3;
        int d0 = (kt / 3) << 5;
        #pragma unroll
        for (int it = 0; it < 2; ++it) {
            int s = (w * 2 + it) * 64 + lane;    // 16B-slot index 0..511
            int p = s >> 3, sl = s & 7;
            int t = sl ^ (p & 7);
            int m = p * 2 + (t >> 2);
            int k8 = t & 3;
            size_t aoff = (size_t)(rowBase + m + kseg) * Cin + d0 + k8 * 8;
            _Float16* lbase = lds_h + nxt * 8192 + (size_t)(w * 2 + it) * 512;
            gll16(Ahi + aoff, lbase);
            gll16(Alo + aoff, lbase + 4096);
        }
    };

    stageA(0, 0);
    for (int kt = 0; kt < nKT; ++kt) {
        const int cur = kt & 1;
        // B fragments for this k-tile: issue before the barrier so the
        // pre-barrier vmcnt drain doubles as their latency cover.
        f16x8 bH[2], bL[2];
        #pragma unroll
        for (int jj = 0; jj < 2; ++jj) {
            int ntg = (n0 + wn + jj * 16) >> 4;
            size_t boff = (((size_t)ntg * nKT + kt) * 64 + lane) * 8;
            bH[jj] = *(const f16x8*)(WfH + boff);
            bL[jj] = *(const f16x8*)(WfL + boff);
        }
        __syncthreads();                          // buf[cur] staged; prior reads of buf[cur^1] done
        if (kt + 1 < nKT) stageA(kt + 1, cur ^ 1);
        const _Float16* lb = lds_h + cur * 8192;
        #pragma unroll
        for (int i = 0; i < 4; ++i) {
            int m = wm + i * 16 + lm;
            int p = m >> 1;
            int sl = (((m & 1) << 2) | lq) ^ (p & 7);
            int off = p * 64 + sl * 8;
            f16x8 aH = *(const f16x8*)(lb + off);
            f16x8 aL = *(const f16x8*)(lb + 4096 + off);
            #pragma unroll
            for (int jj = 0; jj < 2; ++jj) {
                accM[i][jj] = __builtin_amdgcn_mfma_f32_16x16x32_f16(aH, bH[jj], accM[i][jj], 0, 0, 0);
                accC[i][jj] = __builtin_amdgcn_mfma_f32_16x16x32_f16(aH, bL[jj], accC[i][jj], 0, 0, 0);
                accC[i][jj] = __builtin_amdgcn_mfma_f32_16x16x32_f16(aL, bH[jj], accC[i][jj], 0, 0, 0);
            }
        }
    }
    // epilogue: bias + relu + re-split to padded hi/lo output
    #pragma unroll
    for (int i = 0; i < 4; ++i)
        #pragma unroll
        for (int jj = 0; jj < 2; ++jj) {
            int n_g = n0 + wn + jj * 16 + lm;
            float bv = bias[n_g];
            #pragma unroll
            for (int rr = 0; rr < 4; ++rr) {
                int l = l0 + wm + i * 16 + lq * 4 + rr;
                float v = accM[i][jj][rr] + accC[i][jj][rr] * LO_INV + bv;
                v = fmaxf(v, 0.f);
                size_t off = (size_t)(b * PADL + 1 + l) * Cout + n_g;
                split_write(v, Ohi, Olo, off);
            }
        }
}

// ---------------- layernorm in place on split buffer (width 384) -------------
__global__ __launch_bounds__(128) void ln_split_k(
        _Float16* __restrict__ hi, _Float16* __restrict__ lo,
        const float* __restrict__ g, const float* __restrict__ be) {
    const int row = blockIdx.x;
    const int b = row >> 10, l = row & 1023;
    const size_t base = (size_t)(b * PADL + 1 + l) * DD;
    const int tid = threadIdx.x;
    float v0 = split_read(hi, lo, base + tid);
    float v1 = split_read(hi, lo, base + tid + 128);
    float v2 = split_read(hi, lo, base + tid + 256);

    __shared__ float sh[2];
    float s = v0 + v1 + v2;
    #pragma unroll
    for (int o = 32; o > 0; o >>= 1) s += __shfl_down(s, o, 64);
    if ((tid & 63) == 0) sh[tid >> 6] = s;
    __syncthreads();
    float mu = (sh[0] + sh[1]) * (1.f / DD);
    __syncthreads();
    float d0 = v0 - mu, d1 = v1 - mu, d2 = v2 - mu;
    float q = d0 * d0 + d1 * d1 + d2 * d2;
    #pragma unroll
    for (int o = 32; o > 0; o >>= 1) q += __shfl_down(q, o, 64);
    if ((tid & 63) == 0) sh[tid >> 6] = q;
    __syncthreads();
    float var = (sh[0] + sh[1]) * (1.f / DD);
    float rs = rsqrtf(var + 1e-5f);
    split_write(d0 * rs * g[tid] + be[tid], hi, lo, base + tid);
    split_write(d1 * rs * g[tid + 128] + be[tid + 128], hi, lo, base + tid + 128);
    split_write(d2 * rs * g[tid + 256] + be[tid + 256], hi, lo, base + tid + 256);
}

// ---------------- layernorm + length predictor on split buffer ---------------
__global__ __launch_bounds__(128) void ln_pred_split_k(
        const _Float16* __restrict__ hi, const _Float16* __restrict__ lo,
        const float* __restrict__ g, const float* __restrict__ be,
        const float* __restrict__ wl, const float* __restrict__ bl,
        const int* __restrict__ token_lengths, int* __restrict__ lns) {
    const int row = blockIdx.x;
    const int b = row >> 10, l = row & 1023;
    const size_t base = (size_t)(b * PADL + 1 + l) * DD;
    const int tid = threadIdx.x;
    float v0 = split_read(hi, lo, base + tid);
    float v1 = split_read(hi, lo, base + tid + 128);
    float v2 = split_read(hi, lo, base + tid + 256);

    __shared__ float sh[2];
    float s = v0 + v1 + v2;
    #pragma unroll
    for (int o = 32; o > 0; o >>= 1) s += __shfl_down(s, o, 64);
    if ((tid & 63) == 0) sh[tid >> 6] = s;
    __syncthreads();
    float mu = (sh[0] + sh[1]) * (1.f / DD);
    __syncthreads();
    float d0 = v0 - mu, d1 = v1 - mu, d2 = v2 - mu;
    float q = d0 * d0 + d1 * d1 + d2 * d2;
    #pragma unroll
    for (int o = 32; o > 0; o >>= 1) q += __shfl_down(q, o, 64);
    if ((tid & 63) == 0) sh[tid >> 6] = q;
    __syncthreads();
    float var = (sh[0] + sh[1]) * (1.f / DD);
    float rs = rsqrtf(var + 1e-5f);
    __syncthreads();
    float p = (d0 * rs * g[tid]       + be[tid])       * wl[tid]
            + (d1 * rs * g[tid + 128] + be[tid + 128]) * wl[tid + 128]
            + (d2 * rs * g[tid + 256] + be[tid + 256]) * wl[tid + 256];
    #pragma unroll
    for (int o = 32; o > 0; o >>= 1) p += __shfl_down(p, o, 64);
    if ((tid & 63) == 0) sh[tid >> 6] = p;
    __syncthreads();
    if (tid == 0) {
        float pred = sh[0] + sh[1] + bl[0];
        float e = expf(pred);           // ALPHA == 1.0
        float r = rintf(e);             // round-half-even, matches jnp.round
        r = fminf(fmaxf(r, 0.f), (float)MAX_DUR);
        int v = (int)r;
        if (l >= token_lengths[b]) v = 0;
        lns[row] = v;
    }
}

// ---------------- per-batch inclusive cumsum (L=1024) ------------------------
__global__ __launch_bounds__(1024) void cumsum_k(
        const int* __restrict__ lns, int* __restrict__ csum,
        float* __restrict__ totals_out) {
    __shared__ int s[1024];
    const int b = blockIdx.x, tid = threadIdx.x;
    s[tid] = lns[(b << 10) + tid];
    __syncthreads();
    #pragma unroll
    for (int o = 1; o < 1024; o <<= 1) {
        int t = (tid >= o) ? s[tid - o] : 0;
        __syncthreads();
        s[tid] += t;
        __syncthreads();
    }
    csum[(b << 10) + tid] = s[tid];
    if (tid == 1023) totals_out[b] = (float)s[1023];
}

// ---------------- gather: out[b,t,:] = valid ? y[b, idx(t), :] : 0 -----------
__global__ __launch_bounds__(256) void gather_k(
        const float* __restrict__ y, const int* __restrict__ csum,
        float* __restrict__ out) {
    int gid = blockIdx.x * 256 + threadIdx.x;   // B*T_OUT*96 float4 chunks
    int c4 = gid % 96;
    int rest = gid / 96;
    int t = rest % T_OUT;
    int b = rest / T_OUT;
    const int* c = csum + (b << 10);
    int total = c[1023];
    float4 r = make_float4(0.f, 0.f, 0.f, 0.f);
    if (t < total) {
        int lo = 0, hi = 1024;
        while (lo < hi) {               // searchsorted side='right'
            int mid = (lo + hi) >> 1;
            if (c[mid] <= t) lo = mid + 1; else hi = mid;
        }
        int idx = min(lo, LL - 1);
        r = *(const float4*)(y + ((size_t)((b << 10) + idx)) * DD + (c4 << 2));
    }
    *(float4*)(out + ((size_t)b * T_OUT + t) * DD + (c4 << 2)) = r;
}

// ---------------- host side --------------------------------------------------
extern "C" void kernel_launch(void* const* d_in, const int* in_sizes, int n_in,
                              void* d_out, int out_size, void* d_ws, size_t ws_size,
                              hipStream_t stream) {
    const float* y   = (const float*)d_in[0];
    const int*   tok = (const int*)d_in[1];
    const float* w1a = (const float*)d_in[2];
    const float* b1a = (const float*)d_in[3];
    const float* w1b = (const float*)d_in[4];
    const float* b1b = (const float*)d_in[5];
    const float* g1  = (const float*)d_in[6];
    const float* be1 = (const float*)d_in[7];
    const float* w2a = (const float*)d_in[8];
    const float* b2a = (const float*)d_in[9];
    const float* w2b = (const float*)d_in[10];
    const float* b2b = (const float*)d_in[11];
    const float* g2  = (const float*)d_in[12];
    const float* be2 = (const float*)d_in[13];
    const float* wl  = (const float*)d_in[14];
    const float* bl  = (const float*)d_in[15];

    float* out = (float*)d_out;

    // workspace layout (halfs)
    const size_t WN   = (size_t)FF * DD * KK;          // 1,769,472 per weight comp
    const size_t SN   = (size_t)BB * PADL * DD;        // 6,303,744
    const size_t H1N  = (size_t)BB * PADL * FF;        // 25,214,976
    _Float16* p = (_Float16*)d_ws;
    _Float16* Wh1a = p;              _Float16* Wl1a = Wh1a + WN;
    _Float16* Wh1b = Wl1a + WN;      _Float16* Wl1b = Wh1b + WN;
    _Float16* Wh2a = Wl1b + WN;      _Float16* Wl2a = Wh2a + WN;
    _Float16* Wh2b = Wl2a + WN;      _Float16* Wl2b = Wh2b + WN;
    _Float16* Shi  = Wl2b + WN;      _Float16* Slo  = Shi + SN;
    _Float16* H1hi = Slo + SN;       _Float16* H1lo = H1hi + H1N;
    int* lns  = (int*)(H1lo + H1N);
    int* csum = lns + BB * LL;

    const int M = BB * LL;                              // 16384

    // 1) weight frag-pack+split, y split, pad-zero for H1
    {
        int n = FF * DD * KK;
        wfrag_k<<<(n + 255) / 256, 256, 0, stream>>>(w1a, Wh1a, Wl1a, FF, DD);
        wfrag_k<<<(n + 255) / 256, 256, 0, stream>>>(w1b, Wh1b, Wl1b, DD, FF);
        wfrag_k<<<(n + 255) / 256, 256, 0, stream>>>(w2a, Wh2a, Wl2a, FF, DD);
        wfrag_k<<<(n + 255) / 256, 256, 0, stream>>>(w2b, Wh2b, Wl2b, DD, FF);
        int ny = BB * PADL * DD;
        ysplit_k<<<(ny + 255) / 256, 256, 0, stream>>>(y, Shi, Slo);
        int np = BB * 2 * FF;
        padzero_k<<<(np + 255) / 256, 256, 0, stream>>>(H1hi, H1lo, FF);
    }
    // 2) four conv-GEMMs (1-D grids, XCD-remapped in-kernel; block 128x64)
    gemm_split<<<(M / 128) * (FF / 64), 256, 0, stream>>>(Shi, Slo, Wh1a, Wl1a, b1a, H1hi, H1lo, DD, FF, 3 * DD, FF / 64);
    gemm_split<<<(M / 128) * (DD / 64), 256, 0, stream>>>(H1hi, H1lo, Wh1b, Wl1b, b1b, Shi, Slo, FF, DD, 3 * FF, DD / 64);
    ln_split_k<<<M, 128, 0, stream>>>(Shi, Slo, g1, be1);
    gemm_split<<<(M / 128) * (FF / 64), 256, 0, stream>>>(Shi, Slo, Wh2a, Wl2a, b2a, H1hi, H1lo, DD, FF, 3 * DD, FF / 64);
    gemm_split<<<(M / 128) * (DD / 64), 256, 0, stream>>>(H1hi, H1lo, Wh2b, Wl2b, b2b, Shi, Slo, FF, DD, 3 * FF, DD / 64);
    // 3) predictor + cumsum + gather
    ln_pred_split_k<<<M, 128, 0, stream>>>(Shi, Slo, g2, be2, wl, bl, tok, lns);
    cumsum_k<<<BB, 1024, 0, stream>>>(lns, csum, out + (size_t)BB * T_OUT * DD);
    {
        long long n = (long long)BB * T_OUT * 96;
        gather_k<<<(int)((n + 255) / 256), 256, 0, stream>>>(y, csum, out);
    }
}

// Round 8
// 1048.939 us; speedup vs baseline: 2.0392x; 1.0899x over previous
//
#include <hip/hip_runtime.h>
#include <hip/hip_bf16.h>

// Problem constants
#define BB 16
#define LL 1024
#define DD 384
#define FF 1536
#define KK 3
#define T_OUT 10240
#define MAX_DUR 10

#define PADL 1026                 // per-batch padded rows: [0]=zero, [1..1024]=data, [1025]=zero
#define LO_SCALE 2048.0f          // 2^11: keeps lo parts out of fp16-denormal range
#define LO_INV   4.8828125e-4f    // 2^-11

typedef _Float16 f16x8 __attribute__((ext_vector_type(8)));
typedef float    f32x4 __attribute__((ext_vector_type(4)));

__device__ __forceinline__ void gll16(const void* g, void* l) {
    __builtin_amdgcn_global_load_lds(
        (const __attribute__((address_space(1))) void*)g,
        (__attribute__((address_space(3))) void*)l, 16, 0, 0);
}

__device__ __forceinline__ void split_write(float v, _Float16* hi, _Float16* lo, size_t off) {
    _Float16 h = (_Float16)v;
    hi[off] = h;
    lo[off] = (_Float16)((v - (float)h) * LO_SCALE);
}

__device__ __forceinline__ float split_read(const _Float16* hi, const _Float16* lo, size_t off) {
    return (float)hi[off] + (float)lo[off] * LO_INV;
}

// ---- fused weight pack: 4 weights -> MFMA-fragment-major hi/lo -------------
// frag layout: [o_tile16][ktl][lane][e8]; ktl order: kseg=ktl%3, d0=(ktl/3)*32
__global__ void prep_w(const float* __restrict__ w1a, const float* __restrict__ w1b,
                       const float* __restrict__ w2a, const float* __restrict__ w2b,
                       _Float16* __restrict__ base) {
    const int total = FF * 3 * DD;               // same count for all 4
    int id = blockIdx.x * 256 + threadIdx.x;
    int which = id / total;
    int rid = id - which * total;
    if (which >= 4) return;
    const float* w; _Float16 *hi, *lo; int O, I;
    const size_t WN = (size_t)FF * DD * KK;
    if (which == 0)      { w = w1a; O = FF; I = DD; hi = base;          lo = base + WN; }
    else if (which == 1) { w = w1b; O = DD; I = FF; hi = base + 2 * WN; lo = base + 3 * WN; }
    else if (which == 2) { w = w2a; O = FF; I = DD; hi = base + 4 * WN; lo = base + 5 * WN; }
    else                 { w = w2b; O = DD; I = FF; hi = base + 6 * WN; lo = base + 7 * WN; }
    int e = rid & 7;
    int lane = (rid >> 3) & 63;
    int rest = rid >> 9;
    int nKT = (3 * I) >> 5;
    int ktl = rest % nKT;
    int ot = rest / nKT;
    int o = ot * 16 + (lane & 15);
    int koff = ((lane >> 4) << 3) + e;
    int kseg = ktl % 3;
    int i = (ktl / 3) * 32 + koff;
    float v = w[(o * I + i) * 3 + kseg];
    split_write(v, hi, lo, rid);
}

// ---- fused: y split into padded hi/lo + zero H1 halo rows ------------------
__global__ void prep_y(const float* __restrict__ y, _Float16* __restrict__ shi,
                       _Float16* __restrict__ slo, _Float16* __restrict__ h1hi,
                       _Float16* __restrict__ h1lo) {
    const int SNc = BB * PADL * DD;
    int id = blockIdx.x * 256 + threadIdx.x;
    if (id < SNc) {
        int d = id % DD;
        int r = id / DD;
        int b = r / PADL;
        int lr = r - b * PADL;
        float v = 0.f;
        if (lr >= 1 && lr <= LL) v = y[((size_t)(b << 10) + (lr - 1)) * DD + d];
        split_write(v, shi, slo, id);
        return;
    }
    int id2 = id - SNc;                          // BB*2*FF halo elements of H1
    if (id2 >= BB * 2 * FF) return;
    int b = id2 / (2 * FF);
    int rem = id2 - b * 2 * FF;
    int row = (rem / FF) ? (PADL - 1) : 0;
    int c = rem % FF;
    size_t off = (size_t)(b * PADL + row) * FF + c;
    h1hi[off] = (_Float16)0.f;
    h1lo[off] = (_Float16)0.f;
}

// ---------------- split-fp16 MFMA conv-GEMM, BK=64 (2 k-tiles/barrier) -------
// 128x128 block, 4 waves 64x64. A via global_load_lds into 64 KB LDS dbuf
// (2 phases x 2 sub-k-tiles x (hi 8KB|lo 8KB)), same proven swizzle. B direct
// global->reg from fragment-major pack, reloaded per sub-k-tile (single set:
// MFMA reads sources at issue, so WAR on the B regs resolves cheaply).
// Optional split-K: gridDim = nHalf*blocksPerHalf; half h computes k-tiles
// [h*nKTper, (h+1)*nKTper) and writes to its own output (raw, no bias/relu).
__global__ __launch_bounds__(256, 2) void gemm_split(
        const _Float16* __restrict__ Ahi, const _Float16* __restrict__ Alo,
        const _Float16* __restrict__ WfH, const _Float16* __restrict__ WfL,
        const float* __restrict__ bias,
        _Float16* __restrict__ O0hi, _Float16* __restrict__ O0lo,
        _Float16* __restrict__ O1hi, _Float16* __restrict__ O1lo,
        int Cin, int Cout, int nKTper, int nN, int blocksPerHalf, int doRelu) {
    __shared__ _Float16 lds_h[32768];   // 64 KB
    const int tid = threadIdx.x;
    const int lane = tid & 63;
    const int w = tid >> 6;
    const int lm = lane & 15, lq = lane >> 4;
    const int nKTfull = (3 * Cin) >> 5;
    // half decode + XCD-aware remap (group-of-4 m-tiles, n fastest)
    const int half = blockIdx.x / blocksPerHalf;
    const int t2in = blockIdx.x - half * blocksPerHalf;
    const int xcd = t2in & 7;
    const int t2 = t2in >> 3;
    const int g  = t2 / (4 * nN);
    const int r  = t2 - g * (4 * nN);
    const int n_t = r >> 2;
    const int mi  = r & 3;
    const int m_t = ((g * 4 + mi) << 3) + xcd;
    const int m0 = m_t << 7;
    const int n0 = n_t << 7;
    const int b = m0 >> 10;
    const int l0 = m0 & 1023;
    const int rowBase = b * PADL + l0;
    const int wm = (w >> 1) * 64, wn = (w & 1) * 64;
    const int ktBegin = half * nKTper;
    const int ktEnd = ktBegin + nKTper;

    f32x4 accM[4][4], accC[4][4];
    const f32x4 zz = {0.f, 0.f, 0.f, 0.f};
    #pragma unroll
    for (int i = 0; i < 4; ++i)
        #pragma unroll
        for (int jj = 0; jj < 4; ++jj) { accM[i][jj] = zz; accC[i][jj] = zz; }

    // stage A k-tile kt into LDS phase ph, sub-slot sub
    auto stageA = [&](int kt, int ph, int sub) {
        int kseg = kt % 3;
        int d0 = (kt / 3) << 5;
        #pragma unroll
        for (int it = 0; it < 2; ++it) {
            int s = (w * 2 + it) * 64 + lane;    // 16B-slot index 0..511
            int p = s >> 3, sl = s & 7;
            int t = sl ^ (p & 7);
            int m = p * 2 + (t >> 2);
            int k8 = t & 3;
            size_t aoff = (size_t)(rowBase + m + kseg) * Cin + d0 + k8 * 8;
            _Float16* lbase = lds_h + ph * 16384 + sub * 8192 + (w * 2 + it) * 512;
            gll16(Ahi + aoff, lbase);
            gll16(Alo + aoff, lbase + 4096);
        }
    };
    auto loadB = [&](int kt, f16x8* bH, f16x8* bL) {
        #pragma unroll
        for (int jj = 0; jj < 4; ++jj) {
            int ntg = (n0 + wn + jj * 16) >> 4;
            size_t boff = (((size_t)ntg * nKTfull + kt) * 64 + lane) * 8;
            bH[jj] = *(const f16x8*)(WfH + boff);
            bL[jj] = *(const f16x8*)(WfL + boff);
        }
    };
    auto compute = [&](int ph, int sub, const f16x8* bH, const f16x8* bL) {
        const _Float16* lb = lds_h + ph * 16384 + sub * 8192;
        #pragma unroll
        for (int i = 0; i < 4; ++i) {
            int m = wm + i * 16 + lm;
            int p = m >> 1;
            int sl = (((m & 1) << 2) | lq) ^ (p & 7);
            int off = p * 64 + sl * 8;
            f16x8 aH = *(const f16x8*)(lb + off);
            f16x8 aL = *(const f16x8*)(lb + 4096 + off);
            #pragma unroll
            for (int jj = 0; jj < 4; ++jj) {
                accM[i][jj] = __builtin_amdgcn_mfma_f32_16x16x32_f16(aH, bH[jj], accM[i][jj], 0, 0, 0);
                accC[i][jj] = __builtin_amdgcn_mfma_f32_16x16x32_f16(aH, bL[jj], accC[i][jj], 0, 0, 0);
                accC[i][jj] = __builtin_amdgcn_mfma_f32_16x16x32_f16(aL, bH[jj], accC[i][jj], 0, 0, 0);
            }
        }
    };

    f16x8 bH[4], bL[4];
    stageA(ktBegin, 0, 0);
    stageA(ktBegin + 1, 0, 1);
    loadB(ktBegin, bH, bL);
    int ph = 0;
    for (int kt = ktBegin; kt < ktEnd; kt += 2) {   // nKTper even (36 or 72)
        __syncthreads();                             // phase[ph] staged
        if (kt + 2 < ktEnd) { stageA(kt + 2, ph ^ 1, 0); stageA(kt + 3, ph ^ 1, 1); }
        compute(ph, 0, bH, bL);
        loadB(kt + 1, bH, bL);
        compute(ph, 1, bH, bL);
        if (kt + 2 < ktEnd) loadB(kt + 2, bH, bL);   // covered by drain+stage of next phase
        ph ^= 1;
    }
    // epilogue
    _Float16* oh = half ? O1hi : O0hi;
    _Float16* ol = half ? O1lo : O0lo;
    #pragma unroll
    for (int i = 0; i < 4; ++i)
        #pragma unroll
        for (int jj = 0; jj < 4; ++jj) {
            int n_g = n0 + wn + jj * 16 + lm;
            float bv = doRelu ? bias[n_g] : 0.f;
            #pragma unroll
            for (int rr = 0; rr < 4; ++rr) {
                int l = l0 + wm + i * 16 + lq * 4 + rr;
                float v = accM[i][jj][rr] + accC[i][jj][rr] * LO_INV + bv;
                if (doRelu) v = fmaxf(v, 0.f);
                size_t off = (size_t)(b * PADL + 1 + l) * Cout + n_g;
                split_write(v, oh, ol, off);
            }
        }
}

// ---- split-K reduce + bias + relu + LayerNorm (in place over P0) -----------
__global__ __launch_bounds__(128) void reduce_ln_k(
        _Float16* __restrict__ P0hi, _Float16* __restrict__ P0lo,
        const _Float16* __restrict__ P1hi, const _Float16* __restrict__ P1lo,
        const float* __restrict__ bias, const float* __restrict__ g,
        const float* __restrict__ be) {
    const int row = blockIdx.x;
    const int b = row >> 10, l = row & 1023;
    const size_t base = (size_t)(b * PADL + 1 + l) * DD;
    const int tid = threadIdx.x;
    float v0 = split_read(P0hi, P0lo, base + tid)       + split_read(P1hi, P1lo, base + tid)       + bias[tid];
    float v1 = split_read(P0hi, P0lo, base + tid + 128) + split_read(P1hi, P1lo, base + tid + 128) + bias[tid + 128];
    float v2 = split_read(P0hi, P0lo, base + tid + 256) + split_read(P1hi, P1lo, base + tid + 256) + bias[tid + 256];
    v0 = fmaxf(v0, 0.f); v1 = fmaxf(v1, 0.f); v2 = fmaxf(v2, 0.f);

    __shared__ float sh[2];
    float s = v0 + v1 + v2;
    #pragma unroll
    for (int o = 32; o > 0; o >>= 1) s += __shfl_down(s, o, 64);
    if ((tid & 63) == 0) sh[tid >> 6] = s;
    __syncthreads();
    float mu = (sh[0] + sh[1]) * (1.f / DD);
    __syncthreads();
    float d0 = v0 - mu, d1 = v1 - mu, d2 = v2 - mu;
    float q = d0 * d0 + d1 * d1 + d2 * d2;
    #pragma unroll
    for (int o = 32; o > 0; o >>= 1) q += __shfl_down(q, o, 64);
    if ((tid & 63) == 0) sh[tid >> 6] = q;
    __syncthreads();
    float var = (sh[0] + sh[1]) * (1.f / DD);
    float rs = rsqrtf(var + 1e-5f);
    split_write(d0 * rs * g[tid] + be[tid], P0hi, P0lo, base + tid);
    split_write(d1 * rs * g[tid + 128] + be[tid + 128], P0hi, P0lo, base + tid + 128);
    split_write(d2 * rs * g[tid + 256] + be[tid + 256], P0hi, P0lo, base + tid + 256);
}

// ---- split-K reduce + bias + relu + LN + length predictor -> lns -----------
__global__ __launch_bounds__(128) void reduce_ln_pred_k(
        const _Float16* __restrict__ P0hi, const _Float16* __restrict__ P0lo,
        const _Float16* __restrict__ P1hi, const _Float16* __restrict__ P1lo,
        const float* __restrict__ bias, const float* __restrict__ g,
        const float* __restrict__ be, const float* __restrict__ wl,
        const float* __restrict__ bl, const int* __restrict__ token_lengths,
        int* __restrict__ lns) {
    const int row = blockIdx.x;
    const int b = row >> 10, l = row & 1023;
    const size_t base = (size_t)(b * PADL + 1 + l) * DD;
    const int tid = threadIdx.x;
    float v0 = split_read(P0hi, P0lo, base + tid)       + split_read(P1hi, P1lo, base + tid)       + bias[tid];
    float v1 = split_read(P0hi, P0lo, base + tid + 128) + split_read(P1hi, P1lo, base + tid + 128) + bias[tid + 128];
    float v2 = split_read(P0hi, P0lo, base + tid + 256) + split_read(P1hi, P1lo, base + tid + 256) + bias[tid + 256];
    v0 = fmaxf(v0, 0.f); v1 = fmaxf(v1, 0.f); v2 = fmaxf(v2, 0.f);

    __shared__ float sh[2];
    float s = v0 + v1 + v2;
    #pragma unroll
    for (int o = 32; o > 0; o >>= 1) s += __shfl_down(s, o, 64);
    if ((tid & 63) == 0) sh[tid >> 6] = s;
    __syncthreads();
    float mu = (sh[0] + sh[1]) * (1.f / DD);
    __syncthreads();
    float d0 = v0 - mu, d1 = v1 - mu, d2 = v2 - mu;
    float q = d0 * d0 + d1 * d1 + d2 * d2;
    #pragma unroll
    for (int o = 32; o > 0; o >>= 1) q += __shfl_down(q, o, 64);
    if ((tid & 63) == 0) sh[tid >> 6] = q;
    __syncthreads();
    float var = (sh[0] + sh[1]) * (1.f / DD);
    float rs = rsqrtf(var + 1e-5f);
    __syncthreads();
    float p = (d0 * rs * g[tid]       + be[tid])       * wl[tid]
            + (d1 * rs * g[tid + 128] + be[tid + 128]) * wl[tid + 128]
            + (d2 * rs * g[tid + 256] + be[tid + 256]) * wl[tid + 256];
    #pragma unroll
    for (int o = 32; o > 0; o >>= 1) p += __shfl_down(p, o, 64);
    if ((tid & 63) == 0) sh[tid >> 6] = p;
    __syncthreads();
    if (tid == 0) {
        float pred = sh[0] + sh[1] + bl[0];
        float e = expf(pred);           // ALPHA == 1.0
        float r = rintf(e);             // round-half-even, matches jnp.round
        r = fminf(fmaxf(r, 0.f), (float)MAX_DUR);
        int v = (int)r;
        if (l >= token_lengths[b]) v = 0;
        lns[row] = v;
    }
}

// ---------------- per-batch inclusive cumsum (L=1024) ------------------------
__global__ __launch_bounds__(1024) void cumsum_k(
        const int* __restrict__ lns, int* __restrict__ csum,
        float* __restrict__ totals_out) {
    __shared__ int s[1024];
    const int b = blockIdx.x, tid = threadIdx.x;
    s[tid] = lns[(b << 10) + tid];
    __syncthreads();
    #pragma unroll
    for (int o = 1; o < 1024; o <<= 1) {
        int t = (tid >= o) ? s[tid - o] : 0;
        __syncthreads();
        s[tid] += t;
        __syncthreads();
    }
    csum[(b << 10) + tid] = s[tid];
    if (tid == 1023) totals_out[b] = (float)s[1023];
}

// ---------------- idx precompute: one search per (b,t) -----------------------
__global__ __launch_bounds__(256) void idx_k(
        const int* __restrict__ csum, int* __restrict__ idxArr) {
    int id = blockIdx.x * 256 + threadIdx.x;
    if (id >= BB * T_OUT) return;
    int b = id / T_OUT, t = id - b * T_OUT;
    const int* c = csum + (b << 10);
    int total = c[1023];
    int r = -1;
    if (t < total) {
        int lo = 0, hi = 1024;
        while (lo < hi) {               // searchsorted side='right'
            int mid = (lo + hi) >> 1;
            if (c[mid] <= t) lo = mid + 1; else hi = mid;
        }
        r = min(lo, LL - 1);
    }
    idxArr[id] = r;
}

// ---------------- gather: out[b,t,:] = idx>=0 ? y[b, idx, :] : 0 -------------
__global__ __launch_bounds__(256) void gather_k(
        const float* __restrict__ y, const int* __restrict__ idxArr,
        float* __restrict__ out) {
    int gid = blockIdx.x * 256 + threadIdx.x;   // B*T_OUT*96 float4 chunks
    int c4 = gid % 96;
    int rest = gid / 96;
    int t = rest % T_OUT;
    int b = rest / T_OUT;
    int r = idxArr[b * T_OUT + t];
    float4 v = make_float4(0.f, 0.f, 0.f, 0.f);
    if (r >= 0) v = *(const float4*)(y + ((size_t)((b << 10) + r)) * DD + (c4 << 2));
    *(float4*)(out + ((size_t)b * T_OUT + t) * DD + (c4 << 2)) = v;
}

// ---------------- host side --------------------------------------------------
extern "C" void kernel_launch(void* const* d_in, const int* in_sizes, int n_in,
                              void* d_out, int out_size, void* d_ws, size_t ws_size,
                              hipStream_t stream) {
    const float* y   = (const float*)d_in[0];
    const int*   tok = (const int*)d_in[1];
    const float* w1a = (const float*)d_in[2];
    const float* b1a = (const float*)d_in[3];
    const float* w1b = (const float*)d_in[4];
    const float* b1b = (const float*)d_in[5];
    const float* g1  = (const float*)d_in[6];
    const float* be1 = (const float*)d_in[7];
    const float* w2a = (const float*)d_in[8];
    const float* b2a = (const float*)d_in[9];
    const float* w2b = (const float*)d_in[10];
    const float* b2b = (const float*)d_in[11];
    const float* g2  = (const float*)d_in[12];
    const float* be2 = (const float*)d_in[13];
    const float* wl  = (const float*)d_in[14];
    const float* bl  = (const float*)d_in[15];

    float* out = (float*)d_out;

    // workspace layout (halfs): W (8*WN) | S (2*SN) | H1 (2*H1N) | P1 (2*SN)
    const size_t WN   = (size_t)FF * DD * KK;          // 1,769,472
    const size_t SN   = (size_t)BB * PADL * DD;        // 6,303,744
    const size_t H1N  = (size_t)BB * PADL * FF;        // 25,214,976
    _Float16* wsh = (_Float16*)d_ws;
    _Float16* Wh1a = wsh;            _Float16* Wl1a = Wh1a + WN;
    _Float16* Wh1b = Wl1a + WN;      _Float16* Wl1b = Wh1b + WN;
    _Float16* Wh2a = Wl1b + WN;      _Float16* Wl2a = Wh2a + WN;
    _Float16* Wh2b = Wl2a + WN;      _Float16* Wl2b = Wh2b + WN;
    _Float16* Shi  = Wl2b + WN;      _Float16* Slo  = Shi + SN;
    _Float16* H1hi = Slo + SN;       _Float16* H1lo = H1hi + H1N;
    _Float16* P1hi = H1lo + H1N;     _Float16* P1lo = P1hi + SN;
    int* lns    = (int*)(P1lo + SN);
    int* csum   = lns + BB * LL;
    int* idxArr = csum + BB * LL;

    const int M = BB * LL;                              // 16384

    // 1) prep: fused weight pack (1 launch) + fused ysplit/padzero (1 launch)
    prep_w<<<(4 * FF * 3 * DD) / 256, 256, 0, stream>>>(w1a, w1b, w2a, w2b, wsh);
    prep_y<<<(int)((SN + BB * 2 * FF + 255) / 256), 256, 0, stream>>>(y, Shi, Slo, H1hi, H1lo);

    // 2) block 1: FF-GEMM (full K), DD-GEMM split-K=2 -> P0(=S region)+P1, fused reduce+LN
    gemm_split<<<(M / 128) * (FF / 128), 256, 0, stream>>>(
        Shi, Slo, Wh1a, Wl1a, b1a, H1hi, H1lo, H1hi, H1lo,
        DD, FF, (3 * DD) >> 5, FF / 128, (M / 128) * (FF / 128), 1);
    gemm_split<<<2 * (M / 128) * (DD / 128), 256, 0, stream>>>(
        H1hi, H1lo, Wh1b, Wl1b, b1b, Shi, Slo, P1hi, P1lo,
        FF, DD, ((3 * FF) >> 5) / 2, DD / 128, (M / 128) * (DD / 128), 0);
    reduce_ln_k<<<M, 128, 0, stream>>>(Shi, Slo, P1hi, P1lo, b1b, g1, be1);

    // 3) block 2
    gemm_split<<<(M / 128) * (FF / 128), 256, 0, stream>>>(
        Shi, Slo, Wh2a, Wl2a, b2a, H1hi, H1lo, H1hi, H1lo,
        DD, FF, (3 * DD) >> 5, FF / 128, (M / 128) * (FF / 128), 1);
    gemm_split<<<2 * (M / 128) * (DD / 128), 256, 0, stream>>>(
        H1hi, H1lo, Wh2b, Wl2b, b2b, Shi, Slo, P1hi, P1lo,
        FF, DD, ((3 * FF) >> 5) / 2, DD / 128, (M / 128) * (DD / 128), 0);
    reduce_ln_pred_k<<<M, 128, 0, stream>>>(Shi, Slo, P1hi, P1lo, b2b, g2, be2, wl, bl, tok, lns);

    // 4) cumsum + idx + gather
    cumsum_k<<<BB, 1024, 0, stream>>>(lns, csum, out + (size_t)BB * T_OUT * DD);
    idx_k<<<(BB * T_OUT + 255) / 256, 256, 0, stream>>>(csum, idxArr);
    {
        long long n = (long long)BB * T_OUT * 96;
        gather_k<<<(int)((n + 255) / 256), 256, 0, stream>>>(y, idxArr, out);
    }
}